// Round 2
// baseline (495.832 us; speedup 1.0000x reference)
//
#include <hip/hip_runtime.h>

// MS Deformable Attention — fused fp32 kernel.
// Shapes (compile-time constants from the reference):
//   query (16,1000,256) f32 | refp (16,1000,1,4) f32 | value (16,13294,256) f32
//   W_off (256,256) f32 | b_off (256) f32 | W_attn (256,128) f32 | b_attn (128) f32
//   out (16,1000,256) f32
// Levels: (100,100),(50,50),(25,25),(13,13); starts 0,10000,12500,13125; 4 pts each.

#define BS   16
#define LQ   1000
#define LV   13294
#define CDIM 256
#define NH   8
#define HD   32
#define SP   16          // total points per head (4 levels x 4 points)
#define NA   (NH*SP)     // 128 attn logits per query
#define QB   16          // queries per block
#define NBLK ((BS*LQ)/QB) // 1000

__global__ __launch_bounds__(256) void msda_fused(
    const float* __restrict__ query,
    const float* __restrict__ refp,
    const float* __restrict__ value,
    const float* __restrict__ Woff,
    const float* __restrict__ boff,
    const float* __restrict__ Wattn,
    const float* __restrict__ battn,
    float* __restrict__ out)
{
    __shared__ float qlds[QB][CDIM];       // 16 KB
    __shared__ float attn_s[QB][NA];       // 8 KB
    __shared__ float loc_s[QB][NA*2];      // 16 KB
    __shared__ float ref_s[QB][4];

    const int t  = threadIdx.x;
    const int q0 = blockIdx.x * QB;

    // ---- stage queries + reference points into LDS (coalesced) ----
    for (int i = t; i < QB*CDIM; i += 256) {
        qlds[i >> 8][i & 255] = query[(size_t)q0 * CDIM + i];
    }
    if (t < QB*4) {
        ref_s[t >> 2][t & 3] = refp[(size_t)q0 * 4 + t];
    }
    __syncthreads();

    // ---- phase 1: GEMV. thread t owns offset col t; t<128 also owns attn col t ----
    float acc_off[QB];
    float acc_at[QB];
    #pragma unroll
    for (int qq = 0; qq < QB; ++qq) { acc_off[qq] = 0.f; acc_at[qq] = 0.f; }

    const float bo = boff[t];
    const float ba = (t < NA) ? battn[t] : 0.f;

    for (int k4 = 0; k4 < CDIM/4; ++k4) {
        const int k = k4 * 4;
        const float w0 = Woff[(k+0)*CDIM + t];
        const float w1 = Woff[(k+1)*CDIM + t];
        const float w2 = Woff[(k+2)*CDIM + t];
        const float w3 = Woff[(k+3)*CDIM + t];
        #pragma unroll
        for (int qq = 0; qq < QB; ++qq) {
            const float4 qv = *reinterpret_cast<const float4*>(&qlds[qq][k]);
            float a = acc_off[qq];
            a = fmaf(w0, qv.x, a);
            a = fmaf(w1, qv.y, a);
            a = fmaf(w2, qv.z, a);
            a = fmaf(w3, qv.w, a);
            acc_off[qq] = a;
        }
    }
    if (t < NA) {   // waves 0,1 only — wave-uniform branch
        for (int k4 = 0; k4 < CDIM/4; ++k4) {
            const int k = k4 * 4;
            const float w0 = Wattn[(k+0)*NA + t];
            const float w1 = Wattn[(k+1)*NA + t];
            const float w2 = Wattn[(k+2)*NA + t];
            const float w3 = Wattn[(k+3)*NA + t];
            #pragma unroll
            for (int qq = 0; qq < QB; ++qq) {
                const float4 qv = *reinterpret_cast<const float4*>(&qlds[qq][k]);
                float a = acc_at[qq];
                a = fmaf(w0, qv.x, a);
                a = fmaf(w1, qv.y, a);
                a = fmaf(w2, qv.z, a);
                a = fmaf(w3, qv.w, a);
                acc_at[qq] = a;
            }
        }
    }

    // ---- softmax over the 16 points of each head (16-lane shuffle groups) ----
    if (t < NA) {
        #pragma unroll
        for (int qq = 0; qq < QB; ++qq) {
            const float x = acc_at[qq] + ba;
            float m = x;
            #pragma unroll
            for (int d = 1; d < SP; d <<= 1) m = fmaxf(m, __shfl_xor(m, d, 64));
            const float e = __expf(x - m);
            float s = e;
            #pragma unroll
            for (int d = 1; d < SP; d <<= 1) s += __shfl_xor(s, d, 64);
            attn_s[qq][t] = e / s;
        }
    }
    // ---- sampling locations: col t = (h*16+p)*2 + c ----
    {
        const int cc = t & 1;
        #pragma unroll
        for (int qq = 0; qq < QB; ++qq) {
            const float o   = acc_off[qq] + bo;
            const float r   = ref_s[qq][cc];
            const float rwh = ref_s[qq][2 + cc];
            // loc = ref + off * nps(=0.25) * ref_wh * OFFSET_SCALE(=0.5)
            loc_s[qq][t] = fmaf(o * 0.125f, rwh, r);
        }
    }
    __syncthreads();

    // ---- phase 2: bilinear gather + weighted accumulate ----
    const int h = t >> 5;        // head
    const int c = t & (HD-1);    // channel within head
    const int HWs[4] = {100, 50, 25, 13};
    const int Ss[4]  = {0, 10000, 12500, 13125};

    #pragma unroll 1
    for (int qq = 0; qq < QB; ++qq) {
        const int qg = q0 + qq;
        const int b  = qg / LQ;
        const float* __restrict__ vb = value + (size_t)b * LV * CDIM + h*HD + c;
        float acc = 0.f;
        #pragma unroll
        for (int p = 0; p < SP; ++p) {
            const int lvl = p >> 2;
            const int Wl = HWs[lvl];
            const int Hl = HWs[lvl];
            const float lx = loc_s[qq][(h*SP + p)*2 + 0];
            const float ly = loc_s[qq][(h*SP + p)*2 + 1];
            const float a  = attn_s[qq][h*SP + p];

            const float px = lx * (float)Wl - 0.5f;
            const float py = ly * (float)Hl - 0.5f;
            const float fx = floorf(px), fy = floorf(py);
            const int   x0 = (int)fx,   y0 = (int)fy;
            const float wx1 = px - fx,  wy1 = py - fy;
            const float wx0 = 1.f - wx1, wy0 = 1.f - wy1;

            const bool xok0 = (x0 >= 0)   && (x0 < Wl);
            const bool xok1 = (x0 >= -1)  && (x0+1 < Wl);
            const bool yok0 = (y0 >= 0)   && (y0 < Hl);
            const bool yok1 = (y0 >= -1)  && (y0+1 < Hl);

            const float* __restrict__ lb = vb + (size_t)Ss[lvl] * CDIM;
            float v00 = 0.f, v10 = 0.f, v01 = 0.f, v11 = 0.f;
            if (yok0) {
                const float* row = lb + (size_t)(y0 * Wl) * CDIM;
                if (xok0) v00 = row[x0 * CDIM];
                if (xok1) v10 = row[(x0+1) * CDIM];
            }
            if (yok1) {
                const float* row = lb + (size_t)((y0+1) * Wl) * CDIM;
                if (xok0) v01 = row[x0 * CDIM];
                if (xok1) v11 = row[(x0+1) * CDIM];
            }
            acc += a * (v00*(wx0*wy0) + v10*(wx1*wy0) + v01*(wx0*wy1) + v11*(wx1*wy1));
        }
        out[(size_t)qg * CDIM + h*HD + c] = acc;
    }
}

extern "C" void kernel_launch(void* const* d_in, const int* in_sizes, int n_in,
                              void* d_out, int out_size, void* d_ws, size_t ws_size,
                              hipStream_t stream) {
    const float* query = (const float*)d_in[0];
    const float* refp  = (const float*)d_in[1];
    const float* value = (const float*)d_in[2];
    // d_in[3] = value_spatial_shapes (int64) — compile-time constants, unused.
    const float* Woff  = (const float*)d_in[4];
    const float* boff  = (const float*)d_in[5];
    const float* Wattn = (const float*)d_in[6];
    const float* battn = (const float*)d_in[7];
    float* outp = (float*)d_out;

    msda_fused<<<NBLK, 256, 0, stream>>>(query, refp, value, Woff, boff, Wattn, battn, outp);
}

// Round 4
// 400.456 us; speedup vs baseline: 1.2382x; 1.2382x over previous
//
#include <hip/hip_runtime.h>

// MS Deformable Attention — fused fp32 kernel, v2 (resubmit; round-3 infra failure).
// Changes vs v1: QB 16->8 (2000 blocks), LDS union (qlds aliases attn/loc,
// 12.4 KB/block), float4 gather with 4 queries in flight, branchless taps.
//
// Shapes: query (16,1000,256) f32 | refp (16,1000,1,4) | value (16,13294,256)
//   W_off (256,256) | b_off (256) | W_attn (256,128) | b_attn (128)
//   out (16,1000,256) f32
// Levels: (100,100),(50,50),(25,25),(13,13); starts 0,10000,12500,13125.

#define BS   16
#define LQ   1000
#define LV   13294
#define CDIM 256
#define NH   8
#define HD   32
#define SP   16          // total points per head
#define NA   (NH*SP)     // 128 attn logits per query
#define QB   8           // queries per block (8 | 1000 -> block never spans batches)
#define NBLK ((BS*LQ)/QB) // 2000

__global__ __launch_bounds__(256) void msda_fused(
    const float* __restrict__ query,
    const float* __restrict__ refp,
    const float* __restrict__ value,
    const float* __restrict__ Woff,
    const float* __restrict__ boff,
    const float* __restrict__ Wattn,
    const float* __restrict__ battn,
    float* __restrict__ out)
{
    // Union: phase 1 uses qlds[QB][256] (2048 f). Phase 2 uses
    // attn_s[QB][128] (1024 f) + loc_s[QB][256] (2048 f). Total 3072 f = 12 KB.
    __shared__ float smem[QB*NA + QB*CDIM];
    float (*qlds)[CDIM] = (float (*)[CDIM])smem;          // [0, 2048)
    float (*attn_s)[NA] = (float (*)[NA])smem;            // [0, 1024)
    float (*loc_s)[CDIM] = (float (*)[CDIM])(smem + QB*NA); // [1024, 3072)
    __shared__ float ref_s[QB][4];

    const int t  = threadIdx.x;
    const int q0 = blockIdx.x * QB;

    // ---- stage queries + reference points (coalesced) ----
    for (int i = t; i < QB*CDIM; i += 256) {
        qlds[i >> 8][i & 255] = query[(size_t)q0 * CDIM + i];
    }
    if (t < QB*4) {
        ref_s[t >> 2][t & 3] = refp[(size_t)q0 * 4 + t];
    }
    __syncthreads();

    // ---- phase 1: GEMV. thread t owns offset col t; t<128 also owns attn col t ----
    float acc_off[QB];
    float acc_at[QB];
    #pragma unroll
    for (int qq = 0; qq < QB; ++qq) { acc_off[qq] = 0.f; acc_at[qq] = 0.f; }

    const float bo = boff[t];
    const float ba = (t < NA) ? battn[t] : 0.f;

    for (int k4 = 0; k4 < CDIM/4; ++k4) {
        const int k = k4 * 4;
        const float w0 = Woff[(k+0)*CDIM + t];
        const float w1 = Woff[(k+1)*CDIM + t];
        const float w2 = Woff[(k+2)*CDIM + t];
        const float w3 = Woff[(k+3)*CDIM + t];
        #pragma unroll
        for (int qq = 0; qq < QB; ++qq) {
            const float4 qv = *reinterpret_cast<const float4*>(&qlds[qq][k]);
            float a = acc_off[qq];
            a = fmaf(w0, qv.x, a);
            a = fmaf(w1, qv.y, a);
            a = fmaf(w2, qv.z, a);
            a = fmaf(w3, qv.w, a);
            acc_off[qq] = a;
        }
    }
    if (t < NA) {   // waves 0,1 only — wave-uniform branch
        for (int k4 = 0; k4 < CDIM/4; ++k4) {
            const int k = k4 * 4;
            const float w0 = Wattn[(k+0)*NA + t];
            const float w1 = Wattn[(k+1)*NA + t];
            const float w2 = Wattn[(k+2)*NA + t];
            const float w3 = Wattn[(k+3)*NA + t];
            #pragma unroll
            for (int qq = 0; qq < QB; ++qq) {
                const float4 qv = *reinterpret_cast<const float4*>(&qlds[qq][k]);
                float a = acc_at[qq];
                a = fmaf(w0, qv.x, a);
                a = fmaf(w1, qv.y, a);
                a = fmaf(w2, qv.z, a);
                a = fmaf(w3, qv.w, a);
                acc_at[qq] = a;
            }
        }
    }

    // All reads of qlds are done before we overwrite the union with attn/loc.
    __syncthreads();

    // ---- softmax over the 16 points of each head (16-lane shuffle groups) ----
    if (t < NA) {
        #pragma unroll
        for (int qq = 0; qq < QB; ++qq) {
            const float x = acc_at[qq] + ba;
            float m = x;
            #pragma unroll
            for (int d = 1; d < SP; d <<= 1) m = fmaxf(m, __shfl_xor(m, d, 64));
            const float e = __expf(x - m);
            float s = e;
            #pragma unroll
            for (int d = 1; d < SP; d <<= 1) s += __shfl_xor(s, d, 64);
            attn_s[qq][t] = e / s;
        }
    }
    // ---- sampling locations: col t = (h*16+p)*2 + c ----
    {
        const int cc = t & 1;
        #pragma unroll
        for (int qq = 0; qq < QB; ++qq) {
            const float o   = acc_off[qq] + bo;
            const float r   = ref_s[qq][cc];
            const float rwh = ref_s[qq][2 + cc];
            // loc = ref + off * nps(=0.25) * ref_wh * OFFSET_SCALE(=0.5)
            loc_s[qq][t] = fmaf(o * 0.125f, rwh, r);
        }
    }
    __syncthreads();

    // ---- phase 2: bilinear gather, float4 channels, 4 queries in flight ----
    const int sq   = t >> 6;          // which of 4 concurrent queries
    const int lane = t & 63;
    const int h    = lane >> 3;       // head
    const int c4   = (lane & 7) << 2; // channel offset within head (x4)
    const int b    = q0 / LQ;         // uniform: 8 | 1000
    const float* __restrict__ vb = value + (size_t)b * LV * CDIM + h*HD + c4;

    const int HWs[4] = {100, 50, 25, 13};
    const int Ss[4]  = {0, 10000, 12500, 13125};

    #pragma unroll 1
    for (int qq0 = 0; qq0 < QB; qq0 += 4) {
        const int qq = qq0 + sq;
        const int qg = q0 + qq;
        float4 acc = {0.f, 0.f, 0.f, 0.f};
        #pragma unroll 4
        for (int p = 0; p < SP; ++p) {
            const int lvl = p >> 2;
            const int Wl = HWs[lvl];
            const int Hl = HWs[lvl];
            const float lx = loc_s[qq][(h*SP + p)*2 + 0];
            const float ly = loc_s[qq][(h*SP + p)*2 + 1];
            const float a  = attn_s[qq][h*SP + p];

            const float px = lx * (float)Wl - 0.5f;
            const float py = ly * (float)Hl - 0.5f;
            const float fx = floorf(px), fy = floorf(py);
            const int   x0 = (int)fx,   y0 = (int)fy;
            const float wx1 = px - fx,  wy1 = py - fy;
            const float wx0 = 1.f - wx1, wy0 = 1.f - wy1;

            const bool xok0 = (x0 >= 0)  && (x0 < Wl);
            const bool xok1 = (x0 >= -1) && (x0+1 < Wl);
            const bool yok0 = (y0 >= 0)  && (y0 < Hl);
            const bool yok1 = (y0 >= -1) && (y0+1 < Hl);

            // branchless: clamped addresses (always in-bounds), zeroed weights
            const int xc0 = min(max(x0,   0), Wl-1);
            const int xc1 = min(max(x0+1, 0), Wl-1);
            const int yc0 = min(max(y0,   0), Hl-1);
            const int yc1 = min(max(y0+1, 0), Hl-1);

            const float w00 = (xok0 && yok0) ? a*wx0*wy0 : 0.f;
            const float w10 = (xok1 && yok0) ? a*wx1*wy0 : 0.f;
            const float w01 = (xok0 && yok1) ? a*wx0*wy1 : 0.f;
            const float w11 = (xok1 && yok1) ? a*wx1*wy1 : 0.f;

            const float* __restrict__ lb = vb + (size_t)Ss[lvl] * CDIM;
            const float4 v00 = *reinterpret_cast<const float4*>(lb + (size_t)(yc0*Wl + xc0) * CDIM);
            const float4 v10 = *reinterpret_cast<const float4*>(lb + (size_t)(yc0*Wl + xc1) * CDIM);
            const float4 v01 = *reinterpret_cast<const float4*>(lb + (size_t)(yc1*Wl + xc0) * CDIM);
            const float4 v11 = *reinterpret_cast<const float4*>(lb + (size_t)(yc1*Wl + xc1) * CDIM);

            acc.x = fmaf(v00.x, w00, fmaf(v10.x, w10, fmaf(v01.x, w01, fmaf(v11.x, w11, acc.x))));
            acc.y = fmaf(v00.y, w00, fmaf(v10.y, w10, fmaf(v01.y, w01, fmaf(v11.y, w11, acc.y))));
            acc.z = fmaf(v00.z, w00, fmaf(v10.z, w10, fmaf(v01.z, w01, fmaf(v11.z, w11, acc.z))));
            acc.w = fmaf(v00.w, w00, fmaf(v10.w, w10, fmaf(v01.w, w01, fmaf(v11.w, w11, acc.w))));
        }
        *reinterpret_cast<float4*>(&out[(size_t)qg * CDIM + h*HD + c4]) = acc;
    }
}

extern "C" void kernel_launch(void* const* d_in, const int* in_sizes, int n_in,
                              void* d_out, int out_size, void* d_ws, size_t ws_size,
                              hipStream_t stream) {
    const float* query = (const float*)d_in[0];
    const float* refp  = (const float*)d_in[1];
    const float* value = (const float*)d_in[2];
    // d_in[3] = value_spatial_shapes (int64) — compile-time constants, unused.
    const float* Woff  = (const float*)d_in[4];
    const float* boff  = (const float*)d_in[5];
    const float* Wattn = (const float*)d_in[6];
    const float* battn = (const float*)d_in[7];
    float* outp = (float*)d_out;

    msda_fused<<<NBLK, 256, 0, stream>>>(query, refp, value, Woff, boff, Wattn, battn, outp);
}

// Round 5
// 394.064 us; speedup vs baseline: 1.2583x; 1.0162x over previous
//
#include <hip/hip_runtime.h>

// MS Deformable Attention — fused fp32 kernel, v3.
// Changes vs v2: balanced attn-GEMV (k-split across all 256 threads via LDS
// partials), int32 gather addressing (no 64-bit mul chains), 2-query
// interleaved gather for ~2x in-flight loads. Math identical to v2.
//
// Shapes: query (16,1000,256) f32 | refp (16,1000,1,4) | value (16,13294,256)
//   W_off (256,256) | b_off (256) | W_attn (256,128) | b_attn (128)
//   out (16,1000,256) f32
// Levels: (100,100),(50,50),(25,25),(13,13); starts 0,10000,12500,13125.

#define BS   16
#define LQ   1000
#define LV   13294
#define CDIM 256
#define NH   8
#define HD   32
#define SP   16          // total points per head
#define NA   (NH*SP)     // 128 attn logits per query
#define QB   8           // queries per block (block never spans batches)
#define NBLK ((BS*LQ)/QB) // 2000

__global__ __launch_bounds__(256, 3) void msda_fused(
    const float* __restrict__ query,
    const float* __restrict__ refp,
    const float* __restrict__ value,
    const float* __restrict__ Woff,
    const float* __restrict__ boff,
    const float* __restrict__ Wattn,
    const float* __restrict__ battn,
    float* __restrict__ out)
{
    // Union: phase 1 uses qlds[QB][256] (2048 f). Phase 2 uses
    // attn_s[QB][128] (1024 f) + loc_s[QB][256] (2048 f). 12 KB.
    __shared__ float smem[QB*NA + QB*CDIM];
    float (*qlds)[CDIM] = (float (*)[CDIM])smem;             // [0, 2048)
    float (*attn_s)[NA] = (float (*)[NA])smem;               // [0, 1024)
    float (*loc_s)[CDIM] = (float (*)[CDIM])(smem + QB*NA);  // [1024, 3072)
    __shared__ float attn_part[QB][NA][2];                   // 8 KB (k-split partials)
    __shared__ float ref_s[QB][4];

    const int t  = threadIdx.x;
    const int q0 = blockIdx.x * QB;

    // ---- stage queries + reference points (coalesced) ----
    for (int i = t; i < QB*CDIM; i += 256) {
        qlds[i >> 8][i & 255] = query[(size_t)q0 * CDIM + i];
    }
    if (t < QB*4) {
        ref_s[t >> 2][t & 3] = refp[(size_t)q0 * 4 + t];
    }
    __syncthreads();

    // ---- phase 1a: offset GEMV — thread t owns offset col t (256 k) ----
    float acc_off[QB];
    #pragma unroll
    for (int qq = 0; qq < QB; ++qq) acc_off[qq] = 0.f;
    const float bo = boff[t];

    for (int k4 = 0; k4 < CDIM/4; ++k4) {
        const int k = k4 * 4;
        const float w0 = Woff[(k+0)*CDIM + t];
        const float w1 = Woff[(k+1)*CDIM + t];
        const float w2 = Woff[(k+2)*CDIM + t];
        const float w3 = Woff[(k+3)*CDIM + t];
        #pragma unroll
        for (int qq = 0; qq < QB; ++qq) {
            const float4 qv = *reinterpret_cast<const float4*>(&qlds[qq][k]);
            float a = acc_off[qq];
            a = fmaf(w0, qv.x, a);
            a = fmaf(w1, qv.y, a);
            a = fmaf(w2, qv.z, a);
            a = fmaf(w3, qv.w, a);
            acc_off[qq] = a;
        }
    }

    // ---- phase 1b: attn GEMV, balanced — thread t owns col t&127 over
    //      k-half (t>>7); partials combined in softmax ----
    {
        const int ac    = t & (NA-1);
        const int half  = t >> 7;
        const int kbase = half << 7;   // 0 or 128
        float acc_at[QB];
        #pragma unroll
        for (int qq = 0; qq < QB; ++qq) acc_at[qq] = 0.f;

        for (int k4 = 0; k4 < 32; ++k4) {
            const int k = kbase + k4 * 4;
            const float w0 = Wattn[(k+0)*NA + ac];
            const float w1 = Wattn[(k+1)*NA + ac];
            const float w2 = Wattn[(k+2)*NA + ac];
            const float w3 = Wattn[(k+3)*NA + ac];
            #pragma unroll
            for (int qq = 0; qq < QB; ++qq) {
                const float4 qv = *reinterpret_cast<const float4*>(&qlds[qq][k]);
                float a = acc_at[qq];
                a = fmaf(w0, qv.x, a);
                a = fmaf(w1, qv.y, a);
                a = fmaf(w2, qv.z, a);
                a = fmaf(w3, qv.w, a);
                acc_at[qq] = a;
            }
        }
        #pragma unroll
        for (int qq = 0; qq < QB; ++qq) attn_part[qq][ac][half] = acc_at[qq];
    }

    // All qlds reads done before the union is overwritten below.
    __syncthreads();

    // ---- softmax over 16 points per head (16-lane shuffle groups) ----
    if (t < NA) {
        const float ba = battn[t];
        #pragma unroll
        for (int qq = 0; qq < QB; ++qq) {
            const float2 pr = *reinterpret_cast<const float2*>(&attn_part[qq][t][0]);
            const float x = pr.x + pr.y + ba;
            float m = x;
            #pragma unroll
            for (int d = 1; d < SP; d <<= 1) m = fmaxf(m, __shfl_xor(m, d, 64));
            const float e = __expf(x - m);
            float s = e;
            #pragma unroll
            for (int d = 1; d < SP; d <<= 1) s += __shfl_xor(s, d, 64);
            attn_s[qq][t] = e / s;
        }
    }
    // ---- sampling locations: col t = (h*16+p)*2 + c ----
    {
        const int cc = t & 1;
        #pragma unroll
        for (int qq = 0; qq < QB; ++qq) {
            const float o   = acc_off[qq] + bo;
            const float r   = ref_s[qq][cc];
            const float rwh = ref_s[qq][2 + cc];
            // loc = ref + off * nps(=0.25) * ref_wh * OFFSET_SCALE(=0.5)
            loc_s[qq][t] = fmaf(o * 0.125f, rwh, r);
        }
    }
    __syncthreads();

    // ---- phase 2: bilinear gather, float4 channels, 2 queries interleaved ----
    const int sq   = t >> 6;          // 4 concurrent queries across the block
    const int lane = t & 63;
    const int h    = lane >> 3;       // head
    const int c4   = (lane & 7) << 2; // channel offset within head (x4)
    const int b    = q0 / LQ;         // uniform (8 | 1000)
    const float* __restrict__ vb = value + (size_t)b * LV * CDIM + h*HD + c4;

    const int HWs[4] = {100, 50, 25, 13};
    const int Ss[4]  = {0, 10000, 12500, 13125};

    const int qA = sq;
    const int qB2 = sq + 4;
    float4 accA = {0.f, 0.f, 0.f, 0.f};
    float4 accB = {0.f, 0.f, 0.f, 0.f};

    auto tap = [&](int qq, int p, int Wl, int Soff, float4& acc) {
        const int hp = h*SP + p;
        const float lx = loc_s[qq][hp*2 + 0];
        const float ly = loc_s[qq][hp*2 + 1];
        const float a  = attn_s[qq][hp];

        const float px = fmaf(lx, (float)Wl, -0.5f);
        const float py = fmaf(ly, (float)Wl, -0.5f);   // Hl == Wl at every level
        const float fx = floorf(px), fy = floorf(py);
        const int   x0 = (int)fx,   y0 = (int)fy;
        const float wx1 = px - fx,  wy1 = py - fy;
        const float wx0 = 1.f - wx1, wy0 = 1.f - wy1;

        const bool xok0 = (x0 >= 0)  && (x0 < Wl);
        const bool xok1 = (x0 >= -1) && (x0 < Wl-1);
        const bool yok0 = (y0 >= 0)  && (y0 < Wl);
        const bool yok1 = (y0 >= -1) && (y0 < Wl-1);

        const int xc0 = min(max(x0,   0), Wl-1);
        const int xc1 = min(max(x0+1, 0), Wl-1);
        const int yc0 = min(max(y0,   0), Wl-1);
        const int yc1 = min(max(y0+1, 0), Wl-1);

        const float w00 = (xok0 && yok0) ? a*wx0*wy0 : 0.f;
        const float w10 = (xok1 && yok0) ? a*wx1*wy0 : 0.f;
        const float w01 = (xok0 && yok1) ? a*wx0*wy1 : 0.f;
        const float w11 = (xok1 && yok1) ? a*wx1*wy1 : 0.f;

        const int r0 = Soff + yc0*Wl;   // int32 element rows; *CDIM folded as <<8
        const int r1 = Soff + yc1*Wl;
        const float4 v00 = *reinterpret_cast<const float4*>(vb + ((r0 + xc0) << 8));
        const float4 v10 = *reinterpret_cast<const float4*>(vb + ((r0 + xc1) << 8));
        const float4 v01 = *reinterpret_cast<const float4*>(vb + ((r1 + xc0) << 8));
        const float4 v11 = *reinterpret_cast<const float4*>(vb + ((r1 + xc1) << 8));

        acc.x = fmaf(v00.x, w00, fmaf(v10.x, w10, fmaf(v01.x, w01, fmaf(v11.x, w11, acc.x))));
        acc.y = fmaf(v00.y, w00, fmaf(v10.y, w10, fmaf(v01.y, w01, fmaf(v11.y, w11, acc.y))));
        acc.z = fmaf(v00.z, w00, fmaf(v10.z, w10, fmaf(v01.z, w01, fmaf(v11.z, w11, acc.z))));
        acc.w = fmaf(v00.w, w00, fmaf(v10.w, w10, fmaf(v01.w, w01, fmaf(v11.w, w11, acc.w))));
    };

    #pragma unroll 2
    for (int p = 0; p < SP; ++p) {
        const int lvl  = p >> 2;
        const int Wl   = HWs[lvl];
        const int Soff = Ss[lvl];
        tap(qA,  p, Wl, Soff, accA);
        tap(qB2, p, Wl, Soff, accB);
    }

    *reinterpret_cast<float4*>(&out[(size_t)(q0 + qA)  * CDIM + h*HD + c4]) = accA;
    *reinterpret_cast<float4*>(&out[(size_t)(q0 + qB2) * CDIM + h*HD + c4]) = accB;
}

extern "C" void kernel_launch(void* const* d_in, const int* in_sizes, int n_in,
                              void* d_out, int out_size, void* d_ws, size_t ws_size,
                              hipStream_t stream) {
    const float* query = (const float*)d_in[0];
    const float* refp  = (const float*)d_in[1];
    const float* value = (const float*)d_in[2];
    // d_in[3] = value_spatial_shapes (int64) — compile-time constants, unused.
    const float* Woff  = (const float*)d_in[4];
    const float* boff  = (const float*)d_in[5];
    const float* Wattn = (const float*)d_in[6];
    const float* battn = (const float*)d_in[7];
    float* outp = (float*)d_out;

    msda_fused<<<NBLK, 256, 0, stream>>>(query, refp, value, Woff, boff, Wattn, battn, outp);
}